// Round 1
// baseline (595.208 us; speedup 1.0000x reference)
//
#include <hip/hip_runtime.h>

// HVAE ELBO reduction: scalar output.
// Inputs (27): [0..11] z arrays (8192x64 f32), [12..17] Alpha/Beta posterior
// means (64 f32), [18..23] mu_* learned prior means (64 f32),
// [24] edge_logits (8192x8192 f32), [25] edge_index (2x262144 i32),
// [26] num_nodes scalar.

#define NN 8192
#define DD 64
#define NE 262144
#define MASK_WORDS ((size_t)NN * NN / 32)   // 2,097,152 words = 8 MiB

__constant__ const float LOG2PI_F = 1.8378770664093453f;
__constant__ const float LVC_F    = -1.3862943611198906f;   // log(0.25)

struct KLArgs {
    const float4* zm[6];
    const float4* zl[6];
    const float*  pm[6];
};
struct SmallArgs {
    const float* mu[6];     // mu_Alpha..mu_Beta2   (d_in[18..23])
    const float* post[6];   // Alpha_mu..Beta_mu2   (d_in[12..17])
};

// ---------------- reduction helper ----------------
__device__ __forceinline__ void block_reduce_add(float s, double* acc) {
    #pragma unroll
    for (int off = 32; off > 0; off >>= 1) s += __shfl_down(s, off, 64);
    __shared__ double partial[8];
    const int wid  = threadIdx.x >> 6;
    const int lane = threadIdx.x & 63;
    if (lane == 0) partial[wid] = (double)s;
    __syncthreads();
    if (threadIdx.x == 0) {
        double t = partial[0];
        const int nw = blockDim.x >> 6;
        for (int i = 1; i < nw; ++i) t += partial[i];
        atomicAdd(acc, t);
    }
}

// ---------------- adjacency scatter (set semantics via bitmask OR) ----------------
__global__ __launch_bounds__(256) void scatter_kernel(const int* __restrict__ ei,
                                                      unsigned* __restrict__ mask) {
    const unsigned e = blockIdx.x * 256u + threadIdx.x;   // grid sized exactly NE
    const unsigned a = (unsigned)ei[e];
    const unsigned b = (unsigned)ei[NE + e];
    const unsigned p = (a << 13) | b;   // a*8192 + b, fits 26 bits
    const unsigned q = (b << 13) | a;
    atomicOr(&mask[p >> 5], 1u << (p & 31u));
    atomicOr(&mask[q >> 5], 1u << (q & 31u));
}

// ---------------- BCE over edge_logits (256 MB stream) ----------------
__global__ __launch_bounds__(256) void bce_kernel(const float4* __restrict__ x4,
                                                  const unsigned* __restrict__ mask,
                                                  double* __restrict__ acc) {
    const unsigned total4 = (unsigned)((size_t)NN * NN / 4);   // 16,777,216
    const unsigned stride = gridDim.x * 256u;
    float s = 0.f;
    for (unsigned i4 = blockIdx.x * 256u + threadIdx.x; i4 < total4; i4 += stride) {
        const float4 v = x4[i4];
        const unsigned w  = mask[i4 >> 3];          // 8 lanes share one word
        const unsigned sh = (i4 & 7u) << 2;         // 4 bits per float4
        const float xs[4] = {v.x, v.y, v.z, v.w};
        #pragma unroll
        for (int k = 0; k < 4; ++k) {
            const float xv = xs[k];
            const float ax = fabsf(xv);
            float c = fmaxf(xv, 0.f) + log1pf(expf(-ax));
            if ((w >> (sh + k)) & 1u) c -= xv;      // - x*adj (deduped)
            s += c;
        }
    }
    block_reduce_add(s, acc);
}

// ---------------- per-node KL over 6 (z_mu, z_logvar, prior_mu) triples ----------------
__device__ __forceinline__ float kld_elem(float zm, float zl, float pm) {
    const float d = zm - pm;
    // -0.5*(1 + zl - LVC - ((zm-pm)^2 + exp(zl)) / 0.25)
    return -0.5f * (1.0f + zl - LVC_F - (d * d + expf(zl)) * 4.0f);
}

__global__ __launch_bounds__(256) void kl_kernel(KLArgs a, double* __restrict__ acc) {
    const unsigned total4 = NN * DD / 4;            // 131,072
    const unsigned stride = gridDim.x * 256u;
    float s = 0.f;
    for (unsigned i4 = blockIdx.x * 256u + threadIdx.x; i4 < total4; i4 += stride) {
        const unsigned dbase = (i4 & 15u) << 2;     // d index of first elem (D=64)
        #pragma unroll
        for (int t = 0; t < 6; ++t) {
            const float4 zm = a.zm[t][i4];
            const float4 zl = a.zl[t][i4];
            const float4 pm = *(const float4*)(a.pm[t] + dbase);  // L1-broadcast
            s += kld_elem(zm.x, zl.x, pm.x);
            s += kld_elem(zm.y, zl.y, pm.y);
            s += kld_elem(zm.z, zl.z, pm.z);
            s += kld_elem(zm.w, zl.w, pm.w);
        }
    }
    block_reduce_add(s, acc);
}

// ---------------- tiny terms + final combine ----------------
__global__ void final_kernel(SmallArgs sa, const double* __restrict__ acc,
                             float* __restrict__ out) {
    const int d = threadIdx.x;                      // 64 threads, one wave
    float s = 0.f;
    #pragma unroll
    for (int t = 0; t < 6; ++t) {
        const float m = sa.mu[t][d];
        const float q = sa.post[t][d];
        s += -0.5f * (LOG2PI_F + m * m);                         // log_p
        const float diff = m - q;
        s += -0.5f * (1.0f - (diff * diff + 0.25f) * 4.0f);      // extra_kl (equal logvars)
    }
    #pragma unroll
    for (int off = 32; off > 0; off >>= 1) s += __shfl_down(s, off, 64);
    if (d == 0) {
        const double total = (double)s / DD
                           + acc[1] / ((double)NN * DD)
                           + acc[0] / ((double)NN * (double)NN);
        out[0] = (float)total;
    }
}

extern "C" void kernel_launch(void* const* d_in, const int* in_sizes, int n_in,
                              void* d_out, int out_size, void* d_ws, size_t ws_size,
                              hipStream_t stream) {
    (void)in_sizes; (void)n_in; (void)out_size; (void)ws_size;

    double*   acc  = (double*)d_ws;                       // acc[0]=bce, acc[1]=kl
    unsigned* mask = (unsigned*)((char*)d_ws + 256);      // 8 MiB bitmask

    // zero accumulators + bitmask (d_ws is re-poisoned to 0xAA before each call)
    hipMemsetAsync(d_ws, 0, 256 + MASK_WORDS * sizeof(unsigned), stream);

    // build symmetric adjacency bitmask (dedupes duplicate edges & self-loops)
    scatter_kernel<<<NE / 256, 256, 0, stream>>>((const int*)d_in[25], mask);

    // per-node KLs: triples (zm, zl, prior_mu) in reference order
    KLArgs ka;
    const int zmi[6] = {2, 0, 6, 4, 10, 8};   // e, n, e1, n1, e2, n2
    for (int t = 0; t < 6; ++t) {
        ka.zm[t] = (const float4*)d_in[zmi[t]];
        ka.zl[t] = (const float4*)d_in[zmi[t] + 1];
        ka.pm[t] = (const float*)d_in[18 + t];
    }
    kl_kernel<<<512, 256, 0, stream>>>(ka, acc + 1);

    // BCE over 8192^2 logits with bitmask adjacency
    bce_kernel<<<2048, 256, 0, stream>>>((const float4*)d_in[24], mask, acc);

    // tiny vector terms + combine to scalar
    SmallArgs sa;
    for (int t = 0; t < 6; ++t) {
        sa.mu[t]   = (const float*)d_in[18 + t];
        sa.post[t] = (const float*)d_in[12 + t];
    }
    final_kernel<<<1, 64, 0, stream>>>(sa, acc, (float*)d_out);
}

// Round 2
// 452.017 us; speedup vs baseline: 1.3168x; 1.3168x over previous
//
#include <hip/hip_runtime.h>

// HVAE ELBO reduction: scalar output.
// Inputs (27): [0..11] z arrays (8192x64 f32), [12..17] Alpha/Beta posterior
// means (64 f32), [18..23] mu_* learned prior means (64 f32),
// [24] edge_logits (8192x8192 f32), [25] edge_index (2x262144 i32),
// [26] num_nodes scalar.
//
// R1 post-mortem: bce_kernel was VALU-bound (92% VALUBusy, 6.5% HBM) on libm
// expf/log1pf (~300 VALU instrs/elem). R2: hardware transcendentals via
// __expf/__logf (v_exp_f32/v_log_f32), everywhere.

#define NN 8192
#define DD 64
#define NE 262144
#define MASK_WORDS ((size_t)NN * NN / 32)   // 2,097,152 words = 8 MiB

__constant__ const float LOG2PI_F = 1.8378770664093453f;
__constant__ const float LVC_F    = -1.3862943611198906f;   // log(0.25)

struct KLArgs {
    const float4* zm[6];
    const float4* zl[6];
    const float*  pm[6];
};
struct SmallArgs {
    const float* mu[6];     // mu_Alpha..mu_Beta2   (d_in[18..23])
    const float* post[6];   // Alpha_mu..Beta_mu2   (d_in[12..17])
};

// ---------------- reduction helper ----------------
__device__ __forceinline__ void block_reduce_add(float s, double* acc) {
    #pragma unroll
    for (int off = 32; off > 0; off >>= 1) s += __shfl_down(s, off, 64);
    __shared__ double partial[8];
    const int wid  = threadIdx.x >> 6;
    const int lane = threadIdx.x & 63;
    if (lane == 0) partial[wid] = (double)s;
    __syncthreads();
    if (threadIdx.x == 0) {
        double t = partial[0];
        const int nw = blockDim.x >> 6;
        for (int i = 1; i < nw; ++i) t += partial[i];
        atomicAdd(acc, t);
    }
}

// ---------------- adjacency scatter (set semantics via bitmask OR) ----------------
__global__ __launch_bounds__(256) void scatter_kernel(const int* __restrict__ ei,
                                                      unsigned* __restrict__ mask) {
    const unsigned e = blockIdx.x * 256u + threadIdx.x;   // grid sized exactly NE
    const unsigned a = (unsigned)ei[e];
    const unsigned b = (unsigned)ei[NE + e];
    const unsigned p = (a << 13) | b;   // a*8192 + b, fits 26 bits
    const unsigned q = (b << 13) | a;
    atomicOr(&mask[p >> 5], 1u << (p & 31u));
    atomicOr(&mask[q >> 5], 1u << (q & 31u));
}

// ---------------- BCE over edge_logits (256 MB stream) ----------------
__global__ __launch_bounds__(256) void bce_kernel(const float4* __restrict__ x4,
                                                  const unsigned* __restrict__ mask,
                                                  double* __restrict__ acc) {
    const unsigned total4 = (unsigned)((size_t)NN * NN / 4);   // 16,777,216
    const unsigned stride = gridDim.x * 256u;
    float s = 0.f;
    for (unsigned i4 = blockIdx.x * 256u + threadIdx.x; i4 < total4; i4 += stride) {
        const float4 v = x4[i4];
        const unsigned w  = mask[i4 >> 3];          // 8 lanes share one word
        const unsigned sh = (i4 & 7u) << 2;         // 4 bits per float4
        const float xs[4] = {v.x, v.y, v.z, v.w};
        #pragma unroll
        for (int k = 0; k < 4; ++k) {
            const float xv = xs[k];
            const float ax = fabsf(xv);
            // softplus(-|x|) via hardware v_exp_f32 / v_log_f32 (~1 ULP each)
            float c = fmaxf(xv, 0.f) + __logf(1.0f + __expf(-ax));
            if ((w >> (sh + k)) & 1u) c -= xv;      // - x*adj (deduped)
            s += c;
        }
    }
    block_reduce_add(s, acc);
}

// ---------------- per-node KL over 6 (z_mu, z_logvar, prior_mu) triples ----------------
__device__ __forceinline__ float kld_elem(float zm, float zl, float pm) {
    const float d = zm - pm;
    // -0.5*(1 + zl - LVC - ((zm-pm)^2 + exp(zl)) / 0.25)
    return -0.5f * (1.0f + zl - LVC_F - (d * d + __expf(zl)) * 4.0f);
}

__global__ __launch_bounds__(256) void kl_kernel(KLArgs a, double* __restrict__ acc) {
    const unsigned total4 = NN * DD / 4;            // 131,072
    const unsigned stride = gridDim.x * 256u;
    float s = 0.f;
    for (unsigned i4 = blockIdx.x * 256u + threadIdx.x; i4 < total4; i4 += stride) {
        const unsigned dbase = (i4 & 15u) << 2;     // d index of first elem (D=64)
        #pragma unroll
        for (int t = 0; t < 6; ++t) {
            const float4 zm = a.zm[t][i4];
            const float4 zl = a.zl[t][i4];
            const float4 pm = *(const float4*)(a.pm[t] + dbase);  // L1-broadcast
            s += kld_elem(zm.x, zl.x, pm.x);
            s += kld_elem(zm.y, zl.y, pm.y);
            s += kld_elem(zm.z, zl.z, pm.z);
            s += kld_elem(zm.w, zl.w, pm.w);
        }
    }
    block_reduce_add(s, acc);
}

// ---------------- tiny terms + final combine ----------------
__global__ void final_kernel(SmallArgs sa, const double* __restrict__ acc,
                             float* __restrict__ out) {
    const int d = threadIdx.x;                      // 64 threads, one wave
    float s = 0.f;
    #pragma unroll
    for (int t = 0; t < 6; ++t) {
        const float m = sa.mu[t][d];
        const float q = sa.post[t][d];
        s += -0.5f * (LOG2PI_F + m * m);                         // log_p
        const float diff = m - q;
        s += -0.5f * (1.0f - (diff * diff + 0.25f) * 4.0f);      // extra_kl (equal logvars)
    }
    #pragma unroll
    for (int off = 32; off > 0; off >>= 1) s += __shfl_down(s, off, 64);
    if (d == 0) {
        const double total = (double)s / DD
                           + acc[1] / ((double)NN * DD)
                           + acc[0] / ((double)NN * (double)NN);
        out[0] = (float)total;
    }
}

extern "C" void kernel_launch(void* const* d_in, const int* in_sizes, int n_in,
                              void* d_out, int out_size, void* d_ws, size_t ws_size,
                              hipStream_t stream) {
    (void)in_sizes; (void)n_in; (void)out_size; (void)ws_size;

    double*   acc  = (double*)d_ws;                       // acc[0]=bce, acc[1]=kl
    unsigned* mask = (unsigned*)((char*)d_ws + 256);      // 8 MiB bitmask

    // zero accumulators + bitmask (d_ws is re-poisoned to 0xAA before each call)
    hipMemsetAsync(d_ws, 0, 256 + MASK_WORDS * sizeof(unsigned), stream);

    // build symmetric adjacency bitmask (dedupes duplicate edges & self-loops)
    scatter_kernel<<<NE / 256, 256, 0, stream>>>((const int*)d_in[25], mask);

    // per-node KLs: triples (zm, zl, prior_mu) in reference order
    KLArgs ka;
    const int zmi[6] = {2, 0, 6, 4, 10, 8};   // e, n, e1, n1, e2, n2
    for (int t = 0; t < 6; ++t) {
        ka.zm[t] = (const float4*)d_in[zmi[t]];
        ka.zl[t] = (const float4*)d_in[zmi[t] + 1];
        ka.pm[t] = (const float*)d_in[18 + t];
    }
    kl_kernel<<<512, 256, 0, stream>>>(ka, acc + 1);

    // BCE over 8192^2 logits with bitmask adjacency
    bce_kernel<<<2048, 256, 0, stream>>>((const float4*)d_in[24], mask, acc);

    // tiny vector terms + combine to scalar
    SmallArgs sa;
    for (int t = 0; t < 6; ++t) {
        sa.mu[t]   = (const float*)d_in[18 + t];
        sa.post[t] = (const float*)d_in[12 + t];
    }
    final_kernel<<<1, 64, 0, stream>>>(sa, acc, (float*)d_out);
}